// Round 11
// baseline (28.194 us; speedup 1.0000x reference)
//
#include <hip/hip_runtime.h>

#define N1 8192
#define N2 8192
#define KNN 32
#define QPW 4                 // queries per group (block = 1 query group)
#define NSPLIT 4              // candidate slices (= waves per block)
#define SLICE (N2 / NSPLIT)   // 2048 candidates per wave
#define CPL 2                 // candidates per lane per chunk
#define CHUNK (64 * CPL)      // 128 candidates per chunk

// f32(0.1*0.1) -- the reference's weak-promoted threshold (bit-exact vs np ref, rounds 2/7/8/10)
#define R2_F32 0.009999999776482582f

struct F6 { float x0, y0, z0, x1, y1, z1; };

__device__ __forceinline__ F6 ld6(const float* __restrict__ p, int j0) {
    // 24 contiguous bytes per lane (candidates j0, j0+1) -> dwordx4 + dwordx2
    const float* b = p + 3 * j0;
    F6 r;
    r.x0 = b[0]; r.y0 = b[1]; r.z0 = b[2];
    r.x1 = b[3]; r.y1 = b[4]; r.z1 = b[5];
    return r;
}

// popcount(mask & lanemask_lt) in 2 VALU instrs
__device__ __forceinline__ int prefix_lt(unsigned long long m) {
    return (int)__builtin_amdgcn_mbcnt_hi(
        (unsigned)(m >> 32),
        __builtin_amdgcn_mbcnt_lo((unsigned)m, 0u));
}

__global__ __launch_bounds__(256, 8) void ballq_kernel(
    const float* __restrict__ p1, const float* __restrict__ p2,
    float* __restrict__ map_f, float* __restrict__ cnt_f, float* __restrict__ out_f)
{
    // Per-wave hit buffers: slot order within a slice == index order.
    __shared__ float4 buf[NSPLIT][QPW][KNN];   // 8 KB
    __shared__ int    cnts[NSPLIT][QPW];       // uncapped per-slice totals

    const int g    = (int)blockIdx.x;          // query group
    const int h    = (int)(threadIdx.x >> 6);  // slice id 0..3 (wave in block)
    const int lane = (int)(threadIdx.x & 63);
    const int q0   = g * QPW;

    float qx[QPW], qy[QPW], qz[QPW], s1[QPW];
#pragma unroll
    for (int i = 0; i < QPW; ++i) {
        qx[i] = p1[3 * (q0 + i) + 0];
        qy[i] = p1[3 * (q0 + i) + 1];
        qz[i] = p1[3 * (q0 + i) + 2];
        // numpy style: rounded muls, sequential adds, no FMA (bit-exact, do not change)
        s1[i] = __fadd_rn(__fadd_rn(__fmul_rn(qx[i], qx[i]), __fmul_rn(qy[i], qy[i])),
                          __fmul_rn(qz[i], qz[i]));
    }

    int count[QPW] = {0, 0, 0, 0};
    const int jofs = h * SLICE;

    // Bit-exact per-pair classification (do not change): f32 gram trick as numpy
    // computes it. s2 is query-independent -> shared by all QPW queries.
    //
    // Index-order proof for 2 cands/lane: chunk candidates are jb+2l (even, mask m0)
    // and jb+2l+1 (odd, mask m1). Hits before even j=jb+2l: evens l'<l (pre_lt(m0))
    // + odds l'<l (pre_lt(m1)) -> pos0 = count + pre0 + pre1. Hits before odd
    // j=jb+2l+1: evens l'<=l (pre0 + w0) + odds l'<l (pre1) -> pos1 = pos0 + w0.
    auto process = [&](const F6& c, int jb) {
        const int j0 = jb + 2 * lane;
        const float s2a = __fadd_rn(__fadd_rn(__fmul_rn(c.x0, c.x0), __fmul_rn(c.y0, c.y0)),
                                    __fmul_rn(c.z0, c.z0));
        const float s2b = __fadd_rn(__fadd_rn(__fmul_rn(c.x1, c.x1), __fmul_rn(c.y1, c.y1)),
                                    __fmul_rn(c.z1, c.z1));
#pragma unroll
        for (int i = 0; i < QPW; ++i) {
            const float dot0 = __fmaf_rn(qz[i], c.z0, __fmaf_rn(qy[i], c.y0, __fmul_rn(qx[i], c.x0)));
            const float d20  = __fsub_rn(__fadd_rn(s1[i], s2a), __fadd_rn(dot0, dot0));
            const bool  w0   = (d20 <= R2_F32);
            const float dot1 = __fmaf_rn(qz[i], c.z1, __fmaf_rn(qy[i], c.y1, __fmul_rn(qx[i], c.x1)));
            const float d21  = __fsub_rn(__fadd_rn(s1[i], s2b), __fadd_rn(dot1, dot1));
            const bool  w1   = (d21 <= R2_F32);

            const unsigned long long m0 = __ballot(w0);
            const unsigned long long m1 = __ballot(w1);
            if (m0 | m1) {  // one scalar branch per query per 128 candidates
                const int pre0 = prefix_lt(m0);
                const int pre1 = prefix_lt(m1);
                const int pos0 = count[i] + pre0 + pre1;
                const int pos1 = pos0 + (w0 ? 1 : 0);
                if (w0 && pos0 < KNN)
                    buf[h][i][pos0] = make_float4((float)j0, c.x0, c.y0, c.z0);
                if (w1 && pos1 < KNN)
                    buf[h][i][pos1] = make_float4((float)(j0 + 1), c.x1, c.y1, c.z1);
                count[i] += (int)__popcll(m0) + (int)__popcll(m1);
            }
        }
    };

    // Depth-1 register pipeline over 16 chunks of 128 candidates.
    constexpr int NC = SLICE / CHUNK;  // 16
    F6 cur = ld6(p2, jofs + 2 * lane);
#pragma unroll 2
    for (int mc = 0; mc < NC; ++mc) {
        F6 nxt = (mc + 1 < NC) ? ld6(p2, jofs + (mc + 1) * CHUNK + 2 * lane) : cur;
        process(cur, jofs + mc * CHUNK);
        cur = nxt;
        // no early exit: all waves must reach the barrier
    }

    if (lane == 0) {
        cnts[h][0] = count[0];
        cnts[h][1] = count[1];
        cnts[h][2] = count[2];
        cnts[h][3] = count[3];
    }
    __syncthreads();

    // Merge: wave h copies its slots to [start_h, start_h + n_h); disjoint ranges,
    // globally index-ordered. Wave 0 also zero-fills the tail and writes counts.
#pragma unroll
    for (int i = 0; i < QPW; ++i) {
        const int c0 = cnts[0][i];
        const int c1 = cnts[1][i];
        const int c2 = cnts[2][i];
        const int c3 = cnts[3][i];

        int pref = 0;
        if (h > 0) pref += c0;
        if (h > 1) pref += c1;
        if (h > 2) pref += c2;
        int start = pref < KNN ? pref : KNN;
        const int ch = cnts[h][i];
        int nh = KNN - start;
        if (ch < nh) nh = ch;

        if (lane < nh) {
            const float4 f = buf[h][i][lane];
            const int s = (q0 + i) * KNN + start + lane;
            map_f[s] = f.x;
            float* o = out_f + s * 3;
            o[0] = f.y; o[1] = f.z; o[2] = f.w;
        }

        if (h == 0) {
            int total = c0 + c1 + c2 + c3;
            if (total > KNN) total = KNN;
            if (lane < KNN - total) {
                const int s = (q0 + i) * KNN + total + lane;
                map_f[s] = 0.0f;
                float* o = out_f + s * 3;
                o[0] = 0.0f; o[1] = 0.0f; o[2] = 0.0f;
            }
            if (lane == 0) cnt_f[q0 + i] = (float)total;
        }
    }
}

extern "C" void kernel_launch(void* const* d_in, const int* in_sizes, int n_in,
                              void* d_out, int out_size, void* d_ws, size_t ws_size,
                              hipStream_t stream) {
    const float* p1 = (const float*)d_in[0];  // [1, N1, 3] f32
    const float* p2 = (const float*)d_in[1];  // [1, N2, 3] f32
    float* out = (float*)d_out;

    float* map_f = out;                        // N1*KNN (mapping as float)
    float* cnt_f = out + (size_t)N1 * KNN;     // N1 (counts as float)
    float* out_f = cnt_f + N1;                 // N1*KNN*3 (gathered coords)

    dim3 block(256);                           // 4 waves = 4 candidate slices
    dim3 grid(N1 / QPW);                       // 2048 blocks, one query group each
    hipLaunchKernelGGL(ballq_kernel, grid, block, 0, stream,
                       p1, p2, map_f, cnt_f, out_f);
}